// Round 2
// baseline (1510.070 us; speedup 1.0000x reference)
//
#include <hip/hip_runtime.h>
#include <math.h>

#define NEG_SLOPE 0.2f

static __device__ __forceinline__ float leaky(float x) { return x > 0.f ? x : NEG_SLOPE * x; }

// ---------------- utility ----------------

__global__ void zero_int_kernel(int* __restrict__ p, int n) {
    int i = blockIdx.x * blockDim.x + threadIdx.x;
    if (i < n) p[i] = 0;
}

// ---------------- CSR build (edge_index staged as int32 by harness) ----------------

__global__ void count_deg_kernel(const int* __restrict__ ei, int E, int* __restrict__ deg) {
    int stride = gridDim.x * blockDim.x;
    for (int e = blockIdx.x * blockDim.x + threadIdx.x; e < E; e += stride) {
        int d = ei[E + e];
        atomicAdd(&deg[d], 1);
    }
}

__global__ void scan_chunk_kernel(const int* __restrict__ deg, int n,
                                  int* __restrict__ chunk_incl, int* __restrict__ blocksum) {
    __shared__ int tmp[1024];
    int gid = blockIdx.x * 1024 + threadIdx.x;
    int v = (gid < n) ? deg[gid] : 0;
    tmp[threadIdx.x] = v;
    __syncthreads();
    for (int off = 1; off < 1024; off <<= 1) {
        int t = (threadIdx.x >= off) ? tmp[threadIdx.x - off] : 0;
        __syncthreads();
        tmp[threadIdx.x] += t;
        __syncthreads();
    }
    if (gid < n) chunk_incl[gid] = tmp[threadIdx.x];
    if (threadIdx.x == 1023) blocksum[blockIdx.x] = tmp[1023];
}

__global__ void scan_blocksum_kernel(int* blocksum, int nb) {
    if (blockIdx.x == 0 && threadIdx.x == 0) {
        int acc = 0;
        for (int i = 0; i < nb; i++) { int v = blocksum[i]; blocksum[i] = acc; acc += v; }
    }
}

// deg and wptr alias deliberately (each thread reads-then-writes only its own index)
__global__ void finalize_rowptr_kernel(const int* deg, const int* __restrict__ chunk_incl,
                                       const int* __restrict__ blocksum, int n, int E,
                                       int* __restrict__ rowptr, int* wptr) {
    int gid = blockIdx.x * blockDim.x + threadIdx.x;
    if (gid < n) {
        int d = deg[gid];
        int excl = blocksum[gid >> 10] + chunk_incl[gid] - d;
        rowptr[gid] = excl;
        wptr[gid] = excl;
    }
    if (gid == 0) rowptr[n] = E;
}

__global__ void scatter_kernel(const int* __restrict__ ei, int E,
                               int* __restrict__ wptr, int* __restrict__ csr_src) {
    int stride = gridDim.x * blockDim.x;
    for (int e = blockIdx.x * blockDim.x + threadIdx.x; e < E; e += stride) {
        int s = ei[e];
        int d = ei[E + e];
        int pos = atomicAdd(&wptr[d], 1);
        csr_src[pos] = s;
    }
}

// ---------------- Per-layer: GEMM + attention logits ----------------

template <int K>
__global__ __launch_bounds__(256) void gemm_logits_kernel(
        const float* __restrict__ x, const float* __restrict__ W,
        const float* __restrict__ a_src, const float* __restrict__ a_dst, int n,
        float* __restrict__ h, float* __restrict__ esrc, float* __restrict__ edst) {
    __shared__ float Wl[K * 64];
    __shared__ float as[64], ad[64];
    for (int i = threadIdx.x; i < K * 64; i += 256) Wl[i] = W[i];
    if (threadIdx.x < 64) { as[threadIdx.x] = a_src[threadIdx.x]; ad[threadIdx.x] = a_dst[threadIdx.x]; }
    __syncthreads();
    int wave = threadIdx.x >> 6, lane = threadIdx.x & 63;
    for (int row = blockIdx.x * 4 + wave; row < n; row += gridDim.x * 4) {
        const float4* xr = reinterpret_cast<const float4*>(x + (size_t)row * K);
        float acc = 0.f;
#pragma unroll
        for (int k4 = 0; k4 < K / 4; k4++) {
            float4 xv = xr[k4];
            acc += xv.x * Wl[(k4 * 4 + 0) * 64 + lane];
            acc += xv.y * Wl[(k4 * 4 + 1) * 64 + lane];
            acc += xv.z * Wl[(k4 * 4 + 2) * 64 + lane];
            acc += xv.w * Wl[(k4 * 4 + 3) * 64 + lane];
        }
        h[(size_t)row * 64 + lane] = acc;
        float ps = acc * as[lane], pd = acc * ad[lane];
#pragma unroll
        for (int off = 32; off; off >>= 1) {
            ps += __shfl_down(ps, off);
            pd += __shfl_down(pd, off);
        }
        if (lane == 0) { esrc[row] = ps; edst[row] = pd; }
    }
}

// ---------------- Per-layer: softmax + aggregate (one wave per dst) ----------------

__global__ __launch_bounds__(256) void gat_aggregate_kernel(
        const float* __restrict__ h, const float* __restrict__ esrc, const float* __restrict__ edst,
        const int* __restrict__ rowptr, const int* __restrict__ csr_src,
        const float* __restrict__ bias, int n, int do_relu, float* __restrict__ out) {
    int wave = threadIdx.x >> 6, lane = threadIdx.x & 63;
    for (int dst = blockIdx.x * 4 + wave; dst < n; dst += gridDim.x * 4) {
        int rs = rowptr[dst], re = rowptr[dst + 1];
        float ed = edst[dst];
        float eself = leaky(esrc[dst] + ed);
        // online (m, s) per lane; lane 0 seeds the self-loop term
        float m = eself, s = (lane == 0) ? 1.f : 0.f;
        for (int i = rs + lane; i < re; i += 64) {
            int sN = csr_src[i];
            float e = leaky(esrc[sN] + ed);
            float nm = fmaxf(m, e);
            s = s * expf(m - nm) + expf(e - nm);
            m = nm;
        }
#pragma unroll
        for (int off = 32; off; off >>= 1) {
            float m2 = __shfl_down(m, off), s2 = __shfl_down(s, off);
            float nm = fmaxf(m, m2);
            s = s * expf(m - nm) + s2 * expf(m2 - nm);
            m = nm;
        }
        m = __shfl(m, 0);
        s = __shfl(s, 0);
        float inv_s = 1.f / s;
        // self-loop contribution
        float acc = expf(eself - m) * inv_s * h[(size_t)dst * 64 + lane];
        for (int base = rs; base < re; base += 64) {
            int i = base + lane;
            int sN = 0; float w = 0.f;
            if (i < re) {
                sN = csr_src[i];
                w = expf(leaky(esrc[sN] + ed) - m) * inv_s;
            }
            int cnt = min(64, re - base);
            for (int j = 0; j < cnt; j++) {
                float wj = __shfl(w, j);
                int sj = __shfl(sN, j);
                acc += wj * h[(size_t)sj * 64 + lane];
            }
        }
        float v = acc + bias[lane];
        if (do_relu) v = fmaxf(v, 0.f);
        out[(size_t)dst * 64 + lane] = v;
    }
}

// ---------------- launch ----------------

extern "C" void kernel_launch(void* const* d_in, const int* in_sizes, int n_in,
                              void* d_out, int out_size, void* d_ws, size_t ws_size,
                              hipStream_t stream) {
    const float* x = (const float*)d_in[0];
    const int* ei = (const int*)d_in[1];   // harness stages integer inputs as int32
    const float* W1 = (const float*)d_in[2];
    const float* as1 = (const float*)d_in[3];
    const float* ad1 = (const float*)d_in[4];
    const float* b1 = (const float*)d_in[5];
    const float* W2 = (const float*)d_in[6];
    const float* as2 = (const float*)d_in[7];
    const float* ad2 = (const float*)d_in[8];
    const float* b2 = (const float*)d_in[9];
    const float* W3 = (const float*)d_in[10];
    const float* as3 = (const float*)d_in[11];
    const float* ad3 = (const float*)d_in[12];
    const float* b3 = (const float*)d_in[13];

    const int FIN = 128, HID = 64;
    int N = in_sizes[0] / FIN;
    int E = in_sizes[1] / 2;

    char* base = (char*)d_ws;
    size_t off = 0;
    auto alloc = [&](size_t bytes) -> void* {
        void* p = base + off;
        off = (off + bytes + 255) & ~(size_t)255;
        return p;
    };
    int* deg_wptr = (int*)alloc((size_t)N * 4);
    int* rowptr = (int*)alloc((size_t)(N + 1) * 4);
    int* chunk_incl = (int*)alloc((size_t)N * 4);
    int nb = (N + 1023) / 1024;
    int* blocksum = (int*)alloc((size_t)nb * 4);
    int* csr_src = (int*)alloc((size_t)E * 4);
    float* esrc = (float*)alloc((size_t)N * 4);
    float* edst = (float*)alloc((size_t)N * 4);
    float* hA = (float*)alloc((size_t)N * HID * 4);   // single ws h buffer (~40 MB total ws)
    (void)ws_size;
    (void)n_in;

    float* out = (float*)d_out;   // doubles as the ping buffer between layers

    // CSR build (graph identical across the 3 layers)
    zero_int_kernel<<<(N + 255) / 256, 256, 0, stream>>>(deg_wptr, N);
    count_deg_kernel<<<2048, 256, 0, stream>>>(ei, E, deg_wptr);
    scan_chunk_kernel<<<nb, 1024, 0, stream>>>(deg_wptr, N, chunk_incl, blocksum);
    scan_blocksum_kernel<<<1, 64, 0, stream>>>(blocksum, nb);
    finalize_rowptr_kernel<<<(N + 255) / 256, 256, 0, stream>>>(deg_wptr, chunk_incl, blocksum, N, E,
                                                                rowptr, deg_wptr);
    scatter_kernel<<<2048, 256, 0, stream>>>(ei, E, deg_wptr, csr_src);

    int grid = (N + 3) / 4;

    // layer 1: x -> hA -> out (relu)
    gemm_logits_kernel<128><<<grid, 256, 0, stream>>>(x, W1, as1, ad1, N, hA, esrc, edst);
    gat_aggregate_kernel<<<grid, 256, 0, stream>>>(hA, esrc, edst, rowptr, csr_src, b1, N, 1, out);
    // layer 2: out -> hA -> out (relu)
    gemm_logits_kernel<64><<<grid, 256, 0, stream>>>(out, W2, as2, ad2, N, hA, esrc, edst);
    gat_aggregate_kernel<<<grid, 256, 0, stream>>>(hA, esrc, edst, rowptr, csr_src, b2, N, 1, out);
    // layer 3: out -> hA -> out (no relu)
    gemm_logits_kernel<64><<<grid, 256, 0, stream>>>(out, W3, as3, ad3, N, hA, esrc, edst);
    gat_aggregate_kernel<<<grid, 256, 0, stream>>>(hA, esrc, edst, rowptr, csr_src, b3, N, 0, out);
}

// Round 3
// 1273.056 us; speedup vs baseline: 1.1862x; 1.1862x over previous
//
#include <hip/hip_runtime.h>
#include <math.h>

#define NEG_SLOPE 0.2f
#define SH 9            // bin = dst >> SH  (512 dsts per bin)
#define BINW (1 << SH)
#define TILE 4096       // edges per pass-1 tile

static __device__ __forceinline__ float leaky(float x) { return x > 0.f ? x : NEG_SLOPE * x; }

// ---------------- utility ----------------

__global__ void zero_int_kernel(int* __restrict__ p, int n) {
    int i = blockIdx.x * blockDim.x + threadIdx.x;
    if (i < n) p[i] = 0;
}

// ---------------- CSR build (edge_index staged as int32 by harness) ----------------

__global__ void count_deg_kernel(const int* __restrict__ ei, int E, int* __restrict__ deg) {
    int stride = gridDim.x * blockDim.x;
    for (int e = blockIdx.x * blockDim.x + threadIdx.x; e < E; e += stride) {
        int d = ei[E + e];
        atomicAdd(&deg[d], 1);
    }
}

__global__ void scan_chunk_kernel(const int* __restrict__ deg, int n,
                                  int* __restrict__ chunk_incl, int* __restrict__ blocksum) {
    __shared__ int tmp[1024];
    int gid = blockIdx.x * 1024 + threadIdx.x;
    int v = (gid < n) ? deg[gid] : 0;
    tmp[threadIdx.x] = v;
    __syncthreads();
    for (int off = 1; off < 1024; off <<= 1) {
        int t = (threadIdx.x >= off) ? tmp[threadIdx.x - off] : 0;
        __syncthreads();
        tmp[threadIdx.x] += t;
        __syncthreads();
    }
    if (gid < n) chunk_incl[gid] = tmp[threadIdx.x];
    if (threadIdx.x == 1023) blocksum[blockIdx.x] = tmp[1023];
}

__global__ void scan_blocksum_kernel(int* blocksum, int nb) {
    if (blockIdx.x == 0 && threadIdx.x == 0) {
        int acc = 0;
        for (int i = 0; i < nb; i++) { int v = blocksum[i]; blocksum[i] = acc; acc += v; }
    }
}

__global__ void finalize_rowptr_kernel(const int* __restrict__ deg, const int* __restrict__ chunk_incl,
                                       const int* __restrict__ blocksum, int n, int E,
                                       int* __restrict__ rowptr) {
    int gid = blockIdx.x * blockDim.x + threadIdx.x;
    if (gid < n) {
        int d = deg[gid];
        rowptr[gid] = blocksum[gid >> 10] + chunk_incl[gid] - d;
    }
    if (gid == 0) rowptr[n] = E;
}

__global__ void init_bincur_kernel(const int* __restrict__ rowptr, int nbin, int* __restrict__ bin_cur) {
    int b = blockIdx.x * blockDim.x + threadIdx.x;
    if (b < nbin) bin_cur[b] = rowptr[b << SH];
}

// Pass 1: tile-local sort by bin, coalesced staged writes.
// staged entry: (dst & 511) << 17 | src   (needs N <= 131072)
__global__ __launch_bounds__(256) void bin_sort_kernel(const int* __restrict__ ei, int E, int nbin,
                                                       int* __restrict__ bin_cur,
                                                       unsigned* __restrict__ staged) {
    __shared__ unsigned sorted[TILE];
    __shared__ unsigned char binIdx[TILE];
    __shared__ int hist[256];
    __shared__ int binstart[256];
    __shared__ int goff[256];
    int tid = threadIdx.x;
    int tile0 = blockIdx.x * TILE;
    int cnt = min(TILE, E - tile0);
    hist[tid] = 0;
    __syncthreads();
    unsigned mys[16];
    int myb[16], myo[16];
#pragma unroll
    for (int r = 0; r < 16; r++) {
        int idx = tile0 + tid + r * 256;
        if (idx < E) {
            int s = ei[idx], d = ei[E + idx];
            myb[r] = d >> SH;
            mys[r] = ((unsigned)(d & (BINW - 1)) << 17) | (unsigned)s;
            myo[r] = atomicAdd(&hist[myb[r]], 1);
        } else {
            myb[r] = -1;
        }
    }
    __syncthreads();
    int v = hist[tid];
    binstart[tid] = v;
    __syncthreads();
    for (int off = 1; off < 256; off <<= 1) {
        int t = (tid >= off) ? binstart[tid - off] : 0;
        __syncthreads();
        binstart[tid] += t;
        __syncthreads();
    }
    int incl = binstart[tid];
    __syncthreads();
    binstart[tid] = incl - v;   // exclusive scan
    if (tid < nbin && v > 0) goff[tid] = atomicAdd(&bin_cur[tid], v);
    __syncthreads();
#pragma unroll
    for (int r = 0; r < 16; r++) {
        if (myb[r] >= 0) {
            int lp = binstart[myb[r]] + myo[r];
            sorted[lp] = mys[r];
            binIdx[lp] = (unsigned char)myb[r];
        }
    }
    __syncthreads();
    for (int i = tid; i < cnt; i += 256) {
        int b = binIdx[i];
        staged[goff[b] + (i - binstart[b])] = sorted[i];
    }
}

// Pass 2: exact scatter within one bin per workgroup (writes stay L2-local).
__global__ __launch_bounds__(512) void exact_scatter_kernel(const unsigned* __restrict__ staged,
                                                            const int* __restrict__ rowptr, int N,
                                                            int* __restrict__ csr_src) {
    __shared__ int cur[BINW];
    int bin = blockIdx.x;
    int base = bin << SH;
    int nd = min(BINW, N - base);
    for (int t = threadIdx.x; t < nd; t += blockDim.x) cur[t] = rowptr[base + t];
    __syncthreads();
    int start = rowptr[base], end = rowptr[base + nd];
    for (int i = start + (int)threadIdx.x; i < end; i += blockDim.x) {
        unsigned e = staged[i];
        int dl = (int)(e >> 17);
        int src = (int)(e & 0x1FFFFu);
        int pos = atomicAdd(&cur[dl], 1);
        csr_src[pos] = src;
    }
}

// ---------------- Per-layer: GEMM + attention logits ----------------

template <int K>
__global__ __launch_bounds__(256) void gemm_logits_kernel(
        const float* __restrict__ x, const float* __restrict__ W,
        const float* __restrict__ a_src, const float* __restrict__ a_dst, int n,
        float* __restrict__ h, float* __restrict__ esrc, float* __restrict__ edst) {
    __shared__ float Wl[K * 64];
    __shared__ float as[64], ad[64];
    for (int i = threadIdx.x; i < K * 64; i += 256) Wl[i] = W[i];
    if (threadIdx.x < 64) { as[threadIdx.x] = a_src[threadIdx.x]; ad[threadIdx.x] = a_dst[threadIdx.x]; }
    __syncthreads();
    int wave = threadIdx.x >> 6, lane = threadIdx.x & 63;
    for (int row = blockIdx.x * 4 + wave; row < n; row += gridDim.x * 4) {
        const float4* xr = reinterpret_cast<const float4*>(x + (size_t)row * K);
        float acc = 0.f;
#pragma unroll
        for (int k4 = 0; k4 < K / 4; k4++) {
            float4 xv = xr[k4];
            acc += xv.x * Wl[(k4 * 4 + 0) * 64 + lane];
            acc += xv.y * Wl[(k4 * 4 + 1) * 64 + lane];
            acc += xv.z * Wl[(k4 * 4 + 2) * 64 + lane];
            acc += xv.w * Wl[(k4 * 4 + 3) * 64 + lane];
        }
        h[(size_t)row * 64 + lane] = acc;
        float ps = acc * as[lane], pd = acc * ad[lane];
#pragma unroll
        for (int off = 32; off; off >>= 1) {
            ps += __shfl_down(ps, off);
            pd += __shfl_down(pd, off);
        }
        if (lane == 0) { esrc[row] = ps; edst[row] = pd; }
    }
}

// ---------------- Per-layer: softmax + aggregate (one wave per dst) ----------------

__global__ __launch_bounds__(256) void gat_aggregate_kernel(
        const float* __restrict__ h, const float* __restrict__ esrc, const float* __restrict__ edst,
        const int* __restrict__ rowptr, const int* __restrict__ csr_src,
        const float* __restrict__ bias, int n, int do_relu, float* __restrict__ out) {
    int wave = threadIdx.x >> 6, lane = threadIdx.x & 63;
    for (int dst = blockIdx.x * 4 + wave; dst < n; dst += gridDim.x * 4) {
        int rs = rowptr[dst], re = rowptr[dst + 1];
        int deg = re - rs;
        float ed = edst[dst];
        float eself = leaky(esrc[dst] + ed);
        float acc;
        if (deg <= 64) {
            // fast path: whole neighborhood in one wave-load, values stay in registers
            int i = rs + lane;
            bool valid = i < re;
            int sN = valid ? csr_src[i] : 0;
            float e = valid ? leaky(esrc[sN] + ed) : -1e30f;
            float m = fmaxf(e, eself);
#pragma unroll
            for (int off = 32; off; off >>= 1) m = fmaxf(m, __shfl_xor(m, off));
            float p = valid ? expf(e - m) : 0.f;
            float s = p;
#pragma unroll
            for (int off = 32; off; off >>= 1) s += __shfl_xor(s, off);
            float pself = expf(eself - m);
            s += pself;
            float inv_s = 1.f / s;
            acc = pself * inv_s * h[(size_t)dst * 64 + lane];
            float w = p * inv_s;
            for (int j = 0; j < deg; j++) {
                float wj = __shfl(w, j);
                int sj = __shfl(sN, j);
                acc += wj * h[(size_t)sj * 64 + lane];
            }
        } else {
            // general path: online (m, s) per lane; lane 0 seeds the self-loop term
            float m = eself, s = (lane == 0) ? 1.f : 0.f;
            for (int i = rs + lane; i < re; i += 64) {
                int sN = csr_src[i];
                float e = leaky(esrc[sN] + ed);
                float nm = fmaxf(m, e);
                s = s * expf(m - nm) + expf(e - nm);
                m = nm;
            }
#pragma unroll
            for (int off = 32; off; off >>= 1) {
                float m2 = __shfl_xor(m, off), s2 = __shfl_xor(s, off);
                float nm = fmaxf(m, m2);
                s = s * expf(m - nm) + s2 * expf(m2 - nm);
                m = nm;
            }
            float inv_s = 1.f / s;
            acc = expf(eself - m) * inv_s * h[(size_t)dst * 64 + lane];
            for (int base = rs; base < re; base += 64) {
                int i = base + lane;
                int sN = 0;
                float w = 0.f;
                if (i < re) {
                    sN = csr_src[i];
                    w = expf(leaky(esrc[sN] + ed) - m) * inv_s;
                }
                int cnt = min(64, re - base);
                for (int j = 0; j < cnt; j++) {
                    float wj = __shfl(w, j);
                    int sj = __shfl(sN, j);
                    acc += wj * h[(size_t)sj * 64 + lane];
                }
            }
        }
        float v = acc + bias[lane];
        if (do_relu) v = fmaxf(v, 0.f);
        out[(size_t)dst * 64 + lane] = v;
    }
}

// ---------------- launch ----------------

extern "C" void kernel_launch(void* const* d_in, const int* in_sizes, int n_in,
                              void* d_out, int out_size, void* d_ws, size_t ws_size,
                              hipStream_t stream) {
    const float* x = (const float*)d_in[0];
    const int* ei = (const int*)d_in[1];   // harness stages integer inputs as int32
    const float* W1 = (const float*)d_in[2];
    const float* as1 = (const float*)d_in[3];
    const float* ad1 = (const float*)d_in[4];
    const float* b1 = (const float*)d_in[5];
    const float* W2 = (const float*)d_in[6];
    const float* as2 = (const float*)d_in[7];
    const float* ad2 = (const float*)d_in[8];
    const float* b2 = (const float*)d_in[9];
    const float* W3 = (const float*)d_in[10];
    const float* as3 = (const float*)d_in[11];
    const float* ad3 = (const float*)d_in[12];
    const float* b3 = (const float*)d_in[13];

    const int FIN = 128, HID = 64;
    int N = in_sizes[0] / FIN;
    int E = in_sizes[1] / 2;
    int nbin = (N + BINW - 1) >> SH;          // 196 for N=100k (must be <= 256)

    char* base = (char*)d_ws;
    size_t off = 0;
    auto alloc = [&](size_t bytes) -> void* {
        void* p = base + off;
        off = (off + bytes + 255) & ~(size_t)255;
        return p;
    };
    int* deg = (int*)alloc((size_t)N * 4);
    int* rowptr = (int*)alloc((size_t)(N + 1) * 4);
    int* chunk_incl = (int*)alloc((size_t)N * 4);
    int nb = (N + 1023) / 1024;
    int* blocksum = (int*)alloc((size_t)nb * 4);
    int* bin_cur = (int*)alloc((size_t)nbin * 4);
    int* csr_src = (int*)alloc((size_t)E * 4);
    float* esrc = (float*)alloc((size_t)N * 4);
    float* edst = (float*)alloc((size_t)N * 4);
    float* hA = (float*)alloc((size_t)N * HID * 4);
    unsigned* staged = (unsigned*)hA;   // alias: staging is dead before first gemm writes hA
    (void)ws_size;
    (void)n_in;

    float* out = (float*)d_out;   // doubles as the ping buffer between layers

    // ---- CSR build (graph identical across the 3 layers) ----
    zero_int_kernel<<<(N + 255) / 256, 256, 0, stream>>>(deg, N);
    count_deg_kernel<<<2048, 256, 0, stream>>>(ei, E, deg);
    scan_chunk_kernel<<<nb, 1024, 0, stream>>>(deg, N, chunk_incl, blocksum);
    scan_blocksum_kernel<<<1, 64, 0, stream>>>(blocksum, nb);
    finalize_rowptr_kernel<<<(N + 255) / 256, 256, 0, stream>>>(deg, chunk_incl, blocksum, N, E, rowptr);
    init_bincur_kernel<<<(nbin + 255) / 256, 256, 0, stream>>>(rowptr, nbin, bin_cur);
    bin_sort_kernel<<<(E + TILE - 1) / TILE, 256, 0, stream>>>(ei, E, nbin, bin_cur, staged);
    exact_scatter_kernel<<<nbin, 512, 0, stream>>>(staged, rowptr, N, csr_src);

    int grid = (N + 3) / 4;

    // layer 1: x -> hA -> out (relu)
    gemm_logits_kernel<128><<<grid, 256, 0, stream>>>(x, W1, as1, ad1, N, hA, esrc, edst);
    gat_aggregate_kernel<<<grid, 256, 0, stream>>>(hA, esrc, edst, rowptr, csr_src, b1, N, 1, out);
    // layer 2: out -> hA -> out (relu)
    gemm_logits_kernel<64><<<grid, 256, 0, stream>>>(out, W2, as2, ad2, N, hA, esrc, edst);
    gat_aggregate_kernel<<<grid, 256, 0, stream>>>(hA, esrc, edst, rowptr, csr_src, b2, N, 1, out);
    // layer 3: out -> hA -> out (no relu)
    gemm_logits_kernel<64><<<grid, 256, 0, stream>>>(out, W3, as3, ad3, N, hA, esrc, edst);
    gat_aggregate_kernel<<<grid, 256, 0, stream>>>(hA, esrc, edst, rowptr, csr_src, b3, N, 0, out);
}

// Round 4
// 1011.371 us; speedup vs baseline: 1.4931x; 1.2587x over previous
//
#include <hip/hip_runtime.h>
#include <math.h>

#define NEG_SLOPE 0.2f
#define SH 9            // bin = dst >> SH  (512 dsts per bin)
#define BINW (1 << SH)
#define TILE 4096       // edges per pass-1 tile

static __device__ __forceinline__ float leaky(float x) { return x > 0.f ? x : NEG_SLOPE * x; }

// ---------------- utility ----------------

__global__ void zero_int_kernel(int* __restrict__ p, int n) {
    int i = blockIdx.x * blockDim.x + threadIdx.x;
    if (i < n) p[i] = 0;
}

// ---------------- CSR build (edge_index staged as int32 by harness) ----------------

// Bin-level histogram (LDS-aggregated; only 196 global atomic targets per block).
__global__ __launch_bounds__(256) void histo_bins_kernel(const int* __restrict__ ei_dst, int E,
                                                         int* __restrict__ bin_cnt) {
    __shared__ int hl[256];
    hl[threadIdx.x] = 0;
    __syncthreads();
    int stride = gridDim.x * blockDim.x;
    for (int e = blockIdx.x * blockDim.x + threadIdx.x; e < E; e += stride)
        atomicAdd(&hl[ei_dst[e] >> SH], 1);
    __syncthreads();
    int v = hl[threadIdx.x];
    if (v) atomicAdd(&bin_cnt[threadIdx.x], v);
}

// Exclusive scan of bin counts (single workgroup; nbin <= 256).
__global__ void scan_bins_kernel(const int* __restrict__ bin_cnt, int nbin,
                                 int* __restrict__ bin_base, int* __restrict__ bin_cur) {
    __shared__ int buf[256];
    int t = threadIdx.x;
    int v = (t < nbin) ? bin_cnt[t] : 0;
    buf[t] = v;
    __syncthreads();
    for (int off = 1; off < 256; off <<= 1) {
        int tv = (t >= off) ? buf[t - off] : 0;
        __syncthreads();
        buf[t] += tv;
        __syncthreads();
    }
    if (t < nbin) {
        int excl = buf[t] - v;
        bin_base[t] = excl;
        bin_cur[t] = excl;
    }
    if (t == nbin - 1) bin_base[nbin] = buf[t];
}

// Pass 1: tile-local sort by bin, coalesced staged writes.
// staged entry: (dst & 511) << 17 | src   (needs N <= 131072)
__global__ __launch_bounds__(256) void bin_sort_kernel(const int* __restrict__ ei, int E, int nbin,
                                                       int* __restrict__ bin_cur,
                                                       unsigned* __restrict__ staged) {
    __shared__ unsigned sorted[TILE];
    __shared__ unsigned char binIdx[TILE];
    __shared__ int hist[256];
    __shared__ int binstart[256];
    __shared__ int goff[256];
    int tid = threadIdx.x;
    int tile0 = blockIdx.x * TILE;
    int cnt = min(TILE, E - tile0);
    hist[tid] = 0;
    __syncthreads();
    unsigned mys[16];
    int myb[16], myo[16];
#pragma unroll
    for (int r = 0; r < 16; r++) {
        int idx = tile0 + tid + r * 256;
        if (idx < E) {
            int s = ei[idx], d = ei[E + idx];
            myb[r] = d >> SH;
            mys[r] = ((unsigned)(d & (BINW - 1)) << 17) | (unsigned)s;
            myo[r] = atomicAdd(&hist[myb[r]], 1);
        } else {
            myb[r] = -1;
        }
    }
    __syncthreads();
    int v = hist[tid];
    binstart[tid] = v;
    __syncthreads();
    for (int off = 1; off < 256; off <<= 1) {
        int t = (tid >= off) ? binstart[tid - off] : 0;
        __syncthreads();
        binstart[tid] += t;
        __syncthreads();
    }
    int incl = binstart[tid];
    __syncthreads();
    binstart[tid] = incl - v;   // exclusive scan
    if (tid < nbin && v > 0) goff[tid] = atomicAdd(&bin_cur[tid], v);
    __syncthreads();
#pragma unroll
    for (int r = 0; r < 16; r++) {
        if (myb[r] >= 0) {
            int lp = binstart[myb[r]] + myo[r];
            sorted[lp] = mys[r];
            binIdx[lp] = (unsigned char)myb[r];
        }
    }
    __syncthreads();
    for (int i = tid; i < cnt; i += 256) {
        int b = binIdx[i];
        staged[goff[b] + (i - binstart[b])] = sorted[i];
    }
}

// Pass 2 (fused): per bin — count per-dst deg, scan, write rowptr, exact scatter. All LDS-local.
__global__ __launch_bounds__(512) void bin_finalize_kernel(const unsigned* __restrict__ staged,
                                                           const int* __restrict__ bin_base,
                                                           int N, int* __restrict__ rowptr,
                                                           int* __restrict__ csr_src) {
    __shared__ int deg[BINW];      // becomes cursor array after scan
    __shared__ int scanbuf[BINW];
    int bin = blockIdx.x, t = threadIdx.x;
    int base = bin << SH;
    int nd = min(BINW, N - base);
    int bs = bin_base[bin], be = bin_base[bin + 1];
    deg[t] = 0;
    __syncthreads();
    for (int i = bs + t; i < be; i += 512) atomicAdd(&deg[staged[i] >> 17], 1);
    __syncthreads();
    int v = (t < nd) ? deg[t] : 0;
    scanbuf[t] = v;
    __syncthreads();
    for (int off = 1; off < BINW; off <<= 1) {
        int tv = (t >= off) ? scanbuf[t - off] : 0;
        __syncthreads();
        scanbuf[t] += tv;
        __syncthreads();
    }
    int excl = bs + scanbuf[t] - v;
    if (t < nd) rowptr[base + t] = excl;
    if (t == 0) rowptr[base + nd] = be;   // next bin writes same value at its base (benign)
    __syncthreads();
    if (t < nd) deg[t] = excl;            // cursor
    __syncthreads();
    for (int i = bs + t; i < be; i += 512) {
        unsigned e = staged[i];
        int pos = atomicAdd(&deg[e >> 17], 1);
        csr_src[pos] = (int)(e & 0x1FFFFu);
    }
}

// ---------------- Per-layer: register-tiled GEMM + attention logits ----------------
// Block: 128 rows x 64 cols, BK=32. 256 threads, each computes 8 rows x 4 cols.
// Lane map: cg = lane&15 (cols c0=4*cg), rg = lane>>4; thread rows = wv*32 + 4*i + rg.

template <int K>
__global__ __launch_bounds__(256, 4) void gemm_logits_kernel(
        const float* __restrict__ x, const float* __restrict__ W,
        const float* __restrict__ a_src, const float* __restrict__ a_dst, int n,
        float* __restrict__ h, float* __restrict__ esrc, float* __restrict__ edst) {
    __shared__ float xs[128 * 36];     // pad stride 36: read banks conflict-free
    __shared__ float ws[32 * 64];
    const int tid = threadIdx.x;
    const int lane = tid & 63;
    const int wv = tid >> 6;
    const int rg = lane >> 4;
    const int cg = lane & 15;
    const int c0 = cg * 4;
    const int row0 = blockIdx.x * 128;
    const int srow = tid >> 1;          // staging: 2 threads per row
    const int sbase = (tid & 1) * 4;    // float4 slots {sbase..sbase+3}

    float acc[8][4];
#pragma unroll
    for (int i = 0; i < 8; i++)
#pragma unroll
        for (int j = 0; j < 4; j++) acc[i][j] = 0.f;

    for (int k0 = 0; k0 < K; k0 += 32) {
        if (k0) __syncthreads();
        {   // stage x tile (rows row0..row0+127, k0..k0+31)
            int gr = row0 + srow;
            if (gr >= n) gr = n - 1;
            const float4* xr = reinterpret_cast<const float4*>(x + (size_t)gr * K + k0);
#pragma unroll
            for (int j = 0; j < 4; j++) {
                float4 vv = xr[sbase + j];
                *reinterpret_cast<float4*>(&xs[srow * 36 + (sbase + j) * 4]) = vv;
            }
        }
        {   // stage W tile
#pragma unroll
            for (int j = 0; j < 2; j++) {
                int f = tid + 256 * j;
                int k = f >> 4, c4 = (f & 15) * 4;
                *reinterpret_cast<float4*>(&ws[k * 64 + c4]) =
                    *reinterpret_cast<const float4*>(&W[(size_t)(k0 + k) * 64 + c4]);
            }
        }
        __syncthreads();
#pragma unroll
        for (int k4 = 0; k4 < 8; k4++) {
            float4 w0 = *reinterpret_cast<const float4*>(&ws[(k4 * 4 + 0) * 64 + c0]);
            float4 w1 = *reinterpret_cast<const float4*>(&ws[(k4 * 4 + 1) * 64 + c0]);
            float4 w2 = *reinterpret_cast<const float4*>(&ws[(k4 * 4 + 2) * 64 + c0]);
            float4 w3 = *reinterpret_cast<const float4*>(&ws[(k4 * 4 + 3) * 64 + c0]);
#pragma unroll
            for (int i = 0; i < 8; i++) {
                int lr = wv * 32 + i * 4 + rg;
                float4 xv = *reinterpret_cast<const float4*>(&xs[lr * 36 + k4 * 4]);
                acc[i][0] += xv.x * w0.x + xv.y * w1.x + xv.z * w2.x + xv.w * w3.x;
                acc[i][1] += xv.x * w0.y + xv.y * w1.y + xv.z * w2.y + xv.w * w3.y;
                acc[i][2] += xv.x * w0.z + xv.y * w1.z + xv.z * w2.z + xv.w * w3.z;
                acc[i][3] += xv.x * w0.w + xv.y * w1.w + xv.z * w2.w + xv.w * w3.w;
            }
        }
    }

    float as4[4], ad4[4];
#pragma unroll
    for (int j = 0; j < 4; j++) { as4[j] = a_src[c0 + j]; ad4[j] = a_dst[c0 + j]; }
#pragma unroll
    for (int i = 0; i < 8; i++) {
        int r = row0 + wv * 32 + i * 4 + rg;
        float ps = acc[i][0] * as4[0] + acc[i][1] * as4[1] + acc[i][2] * as4[2] + acc[i][3] * as4[3];
        float pd = acc[i][0] * ad4[0] + acc[i][1] * ad4[1] + acc[i][2] * ad4[2] + acc[i][3] * ad4[3];
        ps += __shfl_xor(ps, 1); ps += __shfl_xor(ps, 2); ps += __shfl_xor(ps, 4); ps += __shfl_xor(ps, 8);
        pd += __shfl_xor(pd, 1); pd += __shfl_xor(pd, 2); pd += __shfl_xor(pd, 4); pd += __shfl_xor(pd, 8);
        if (r < n) {
            float4 hv = make_float4(acc[i][0], acc[i][1], acc[i][2], acc[i][3]);
            *reinterpret_cast<float4*>(&h[(size_t)r * 64 + c0]) = hv;
            if (cg == 0) { esrc[r] = ps; edst[r] = pd; }
        }
    }
}

// ---------------- Per-layer: softmax + aggregate (one wave per dst) ----------------

#define GATHER8(J)                                                                  \
    {                                                                               \
        float w0 = __shfl(w, (J) + 0), w1 = __shfl(w, (J) + 1);                     \
        float w2 = __shfl(w, (J) + 2), w3 = __shfl(w, (J) + 3);                     \
        float w4_ = __shfl(w, (J) + 4), w5 = __shfl(w, (J) + 5);                    \
        float w6 = __shfl(w, (J) + 6), w7 = __shfl(w, (J) + 7);                     \
        int s0 = __shfl(sN, (J) + 0), s1 = __shfl(sN, (J) + 1);                     \
        int s2 = __shfl(sN, (J) + 2), s3 = __shfl(sN, (J) + 3);                     \
        int s4 = __shfl(sN, (J) + 4), s5 = __shfl(sN, (J) + 5);                     \
        int s6 = __shfl(sN, (J) + 6), s7 = __shfl(sN, (J) + 7);                     \
        float g0 = h[(size_t)s0 * 64 + lane], g1 = h[(size_t)s1 * 64 + lane];       \
        float g2 = h[(size_t)s2 * 64 + lane], g3 = h[(size_t)s3 * 64 + lane];       \
        float g4 = h[(size_t)s4 * 64 + lane], g5 = h[(size_t)s5 * 64 + lane];       \
        float g6 = h[(size_t)s6 * 64 + lane], g7 = h[(size_t)s7 * 64 + lane];       \
        acc += w0 * g0; acc += w1 * g1; acc += w2 * g2; acc += w3 * g3;             \
        acc += w4_ * g4; acc += w5 * g5; acc += w6 * g6; acc += w7 * g7;            \
    }

__global__ __launch_bounds__(256) void gat_aggregate_kernel(
        const float* __restrict__ h, const float* __restrict__ esrc, const float* __restrict__ edst,
        const int* __restrict__ rowptr, const int* __restrict__ csr_src,
        const float* __restrict__ bias, int n, int do_relu, float* __restrict__ out) {
    int wave = threadIdx.x >> 6, lane = threadIdx.x & 63;
    for (int dst = blockIdx.x * 4 + wave; dst < n; dst += gridDim.x * 4) {
        int rs = rowptr[dst], re = rowptr[dst + 1];
        int deg = re - rs;
        float ed = edst[dst];
        float eself = leaky(esrc[dst] + ed);
        float acc;
        if (deg <= 64) {
            int i = rs + lane;
            bool valid = i < re;
            int sN = valid ? csr_src[i] : 0;
            float e = valid ? leaky(esrc[sN] + ed) : -1e30f;
            float m = fmaxf(e, eself);
#pragma unroll
            for (int off = 32; off; off >>= 1) m = fmaxf(m, __shfl_xor(m, off));
            float p = valid ? expf(e - m) : 0.f;
            float s = p;
#pragma unroll
            for (int off = 32; off; off >>= 1) s += __shfl_xor(s, off);
            float pself = expf(eself - m);
            s += pself;
            float inv_s = 1.f / s;
            acc = pself * inv_s * h[(size_t)dst * 64 + lane];
            float w = p * inv_s;
            int j = 0;
            for (; j + 8 <= deg; j += 8) GATHER8(j);
            for (; j < deg; j++) {
                float wj = __shfl(w, j);
                int sj = __shfl(sN, j);
                acc += wj * h[(size_t)sj * 64 + lane];
            }
        } else {
            float m = eself, s = (lane == 0) ? 1.f : 0.f;
            for (int i = rs + lane; i < re; i += 64) {
                int sN = csr_src[i];
                float e = leaky(esrc[sN] + ed);
                float nm = fmaxf(m, e);
                s = s * expf(m - nm) + expf(e - nm);
                m = nm;
            }
#pragma unroll
            for (int off = 32; off; off >>= 1) {
                float m2 = __shfl_xor(m, off), s2 = __shfl_xor(s, off);
                float nm = fmaxf(m, m2);
                s = s * expf(m - nm) + s2 * expf(m2 - nm);
                m = nm;
            }
            float inv_s = 1.f / s;
            acc = expf(eself - m) * inv_s * h[(size_t)dst * 64 + lane];
            for (int base = rs; base < re; base += 64) {
                int i = base + lane;
                int sN = 0;
                float w = 0.f;
                if (i < re) {
                    sN = csr_src[i];
                    w = expf(leaky(esrc[sN] + ed) - m) * inv_s;
                }
                int cnt = min(64, re - base);
                int j = 0;
                for (; j + 8 <= cnt; j += 8) GATHER8(j);
                for (; j < cnt; j++) {
                    float wj = __shfl(w, j);
                    int sj = __shfl(sN, j);
                    acc += wj * h[(size_t)sj * 64 + lane];
                }
            }
        }
        float v = acc + bias[lane];
        if (do_relu) v = fmaxf(v, 0.f);
        out[(size_t)dst * 64 + lane] = v;
    }
}

// ---------------- launch ----------------

extern "C" void kernel_launch(void* const* d_in, const int* in_sizes, int n_in,
                              void* d_out, int out_size, void* d_ws, size_t ws_size,
                              hipStream_t stream) {
    const float* x = (const float*)d_in[0];
    const int* ei = (const int*)d_in[1];   // harness stages integer inputs as int32
    const float* W1 = (const float*)d_in[2];
    const float* as1 = (const float*)d_in[3];
    const float* ad1 = (const float*)d_in[4];
    const float* b1 = (const float*)d_in[5];
    const float* W2 = (const float*)d_in[6];
    const float* as2 = (const float*)d_in[7];
    const float* ad2 = (const float*)d_in[8];
    const float* b2 = (const float*)d_in[9];
    const float* W3 = (const float*)d_in[10];
    const float* as3 = (const float*)d_in[11];
    const float* ad3 = (const float*)d_in[12];
    const float* b3 = (const float*)d_in[13];

    const int FIN = 128, HID = 64;
    int N = in_sizes[0] / FIN;
    int E = in_sizes[1] / 2;
    int nbin = (N + BINW - 1) >> SH;          // 196 for N=100k (must be <= 256)

    char* base = (char*)d_ws;
    size_t off = 0;
    auto alloc = [&](size_t bytes) -> void* {
        void* p = base + off;
        off = (off + bytes + 255) & ~(size_t)255;
        return p;
    };
    int* rowptr = (int*)alloc((size_t)(N + 1) * 4);
    int* bin_cnt = (int*)alloc((size_t)nbin * 4);
    int* bin_base = (int*)alloc((size_t)(nbin + 1) * 4);
    int* bin_cur = (int*)alloc((size_t)nbin * 4);
    int* csr_src = (int*)alloc((size_t)E * 4);
    float* esrc = (float*)alloc((size_t)N * 4);
    float* edst = (float*)alloc((size_t)N * 4);
    float* hA = (float*)alloc((size_t)N * HID * 4);
    unsigned* staged = (unsigned*)hA;   // alias: staging is dead before first gemm writes hA
    (void)ws_size;
    (void)n_in;

    float* out = (float*)d_out;   // doubles as the ping buffer between layers

    // ---- CSR build (graph identical across the 3 layers; no per-dst global atomics) ----
    zero_int_kernel<<<1, 256, 0, stream>>>(bin_cnt, nbin);
    histo_bins_kernel<<<2048, 256, 0, stream>>>(ei + E, E, bin_cnt);
    scan_bins_kernel<<<1, 256, 0, stream>>>(bin_cnt, nbin, bin_base, bin_cur);
    bin_sort_kernel<<<(E + TILE - 1) / TILE, 256, 0, stream>>>(ei, E, nbin, bin_cur, staged);
    bin_finalize_kernel<<<nbin, 512, 0, stream>>>(staged, bin_base, N, rowptr, csr_src);

    int agrid = (N + 3) / 4;
    int ggrid = (N + 127) / 128;

    // layer 1: x -> hA -> out (relu)
    gemm_logits_kernel<128><<<ggrid, 256, 0, stream>>>(x, W1, as1, ad1, N, hA, esrc, edst);
    gat_aggregate_kernel<<<agrid, 256, 0, stream>>>(hA, esrc, edst, rowptr, csr_src, b1, N, 1, out);
    // layer 2: out -> hA -> out (relu)
    gemm_logits_kernel<64><<<ggrid, 256, 0, stream>>>(out, W2, as2, ad2, N, hA, esrc, edst);
    gat_aggregate_kernel<<<agrid, 256, 0, stream>>>(hA, esrc, edst, rowptr, csr_src, b2, N, 1, out);
    // layer 3: out -> hA -> out (no relu)
    gemm_logits_kernel<64><<<ggrid, 256, 0, stream>>>(out, W3, as3, ad3, N, hA, esrc, edst);
    gat_aggregate_kernel<<<agrid, 256, 0, stream>>>(hA, esrc, edst, rowptr, csr_src, b3, N, 0, out);
}